// Round 17
// baseline (32.782 us; speedup 1.0000x reference)
//
#include <hip/hip_runtime.h>

#define NPTS 4096
#define BATCH 8
#define BLK 256
#define PPT 8                        // p-points per thread
#define NPB (BLK * PPT)              // 2048 p-points per block
#define MCH 256                      // q-points staged in LDS per block
#define NCHUNK (NPTS / MCH)          // 16
#define PGRP (NPTS / NPB)            // 2
#define FBLK 1024                    // finalize threads (= NPTS/4 float4s)

// ---------------------------------------------------------------------------
// Kernel 1: partial min over one q-chunk. R16 champion, unchanged.
// ---------------------------------------------------------------------------
__global__ __launch_bounds__(BLK, 2) void dmin_kernel(
    const float* __restrict__ X, const float* __restrict__ Y,
    float* __restrict__ partial, unsigned int* __restrict__ ticket) {
  if (blockIdx.x == 0 && blockIdx.y == 0 && blockIdx.z == 0 &&
      threadIdx.x == 0) {
    __hip_atomic_store(ticket, 0u, __ATOMIC_RELAXED, __HIP_MEMORY_SCOPE_AGENT);
  }

  const int pg    = blockIdx.x;
  const int b     = blockIdx.y;
  const int chunk = blockIdx.z & (NCHUNK - 1);
  const int dir   = blockIdx.z >> 4;
  const float* pts = dir ? Y : X;  // set we compute mins for
  const float* oth = dir ? X : Y;  // set we min over

  __shared__ float4 s[MCH];  // 4 KB, AoS (-2qx,-2qy,-2qz,|q|^2)
  const float* othb = oth + ((size_t)b * NPTS + (size_t)chunk * MCH) * 3;
  {
    const int i = threadIdx.x;  // MCH == BLK: one q per thread
    float qx = othb[3 * i], qy = othb[3 * i + 1], qz = othb[3 * i + 2];
    s[i] = make_float4(-2.f * qx, -2.f * qy, -2.f * qz,
                       qx * qx + qy * qy + qz * qz);
  }
  __syncthreads();

  const int n0 = pg * NPB + threadIdx.x * PPT;  // 8 consecutive p-points
  const float4* pv4 = (const float4*)(pts + ((size_t)b * NPTS + n0) * 3);
  const float4 A = pv4[0], B = pv4[1], C = pv4[2];
  const float4 D = pv4[3], E = pv4[4], F = pv4[5];
  float px[PPT], py[PPT], pz[PPT];
  px[0] = A.x; py[0] = A.y; pz[0] = A.z;
  px[1] = A.w; py[1] = B.x; pz[1] = B.y;
  px[2] = B.z; py[2] = B.w; pz[2] = C.x;
  px[3] = C.y; py[3] = C.z; pz[3] = C.w;
  px[4] = D.x; py[4] = D.y; pz[4] = D.z;
  px[5] = D.w; py[5] = E.x; pz[5] = E.y;
  px[6] = E.z; py[6] = E.w; pz[6] = F.x;
  px[7] = F.y; py[7] = F.z; pz[7] = F.w;

  float acc[2 * PPT];
#pragma unroll
  for (int i = 0; i < 2 * PPT; ++i) acc[i] = 3.4e38f;

#define COMPUTE(q0, q1, q2, q3)                                               \
  {                                                                           \
    _Pragma("unroll")                                                         \
    for (int pp = 0; pp < PPT; ++pp) {                                        \
      float d0 = fmaf(px[pp], q0.x,                                           \
                 fmaf(py[pp], q0.y, fmaf(pz[pp], q0.z, q0.w)));               \
      float d1 = fmaf(px[pp], q1.x,                                           \
                 fmaf(py[pp], q1.y, fmaf(pz[pp], q1.z, q1.w)));               \
      float d2 = fmaf(px[pp], q2.x,                                           \
                 fmaf(py[pp], q2.y, fmaf(pz[pp], q2.z, q2.w)));               \
      float d3 = fmaf(px[pp], q3.x,                                           \
                 fmaf(py[pp], q3.y, fmaf(pz[pp], q3.z, q3.w)));               \
      acc[2 * pp]     = fminf(fminf(acc[2 * pp], d0), d1);     /* v_min3 */   \
      acc[2 * pp + 1] = fminf(fminf(acc[2 * pp + 1], d2), d3); /* v_min3 */   \
    }                                                                         \
  }

  float4 c0 = s[0], c1 = s[1], c2 = s[2], c3 = s[3];
#pragma unroll 2
  for (int m = 0; m < MCH - 4; m += 4) {
    float4 t0 = s[m + 4], t1 = s[m + 5], t2 = s[m + 6], t3 = s[m + 7];
    COMPUTE(c0, c1, c2, c3);
    c0 = t0; c1 = t1; c2 = t2; c3 = t3;
  }
  COMPUTE(c0, c1, c2, c3);
#undef COMPUTE

  float r[PPT];
#pragma unroll
  for (int pp = 0; pp < PPT; ++pp) {
    float c = px[pp] * px[pp] + py[pp] * py[pp] + pz[pp] * pz[pp];
    r[pp] = fminf(acc[2 * pp], acc[2 * pp + 1]) + c;
  }
  float* dst = &partial[(((size_t)chunk * 2 + dir) * BATCH + b) * NPTS + n0];
  ((float4*)dst)[0] = make_float4(r[0], r[1], r[2], r[3]);
  ((float4*)dst)[1] = make_float4(r[4], r[5], r[6], r[7]);
}

// ---------------------------------------------------------------------------
// Kernel 2: 16 blocks x 1024 threads, block w = (dir,b). Each thread owns
// exactly ONE float4 (1024 x 4 = 4096 = NPTS): 16 independent chunk-min loads
// all in flight, then block-wide {sum,ssq} reduction (wave shuffle + 16-wave
// LDS tree), one-pass ddof=1 var, strict mask pass from registers, same
// reduction, fixed order everywhere -> res[w]; last block via ticket sums
// res[0..15] in fixed index order -> out[0]. Bit-deterministic, no memset.
// ---------------------------------------------------------------------------
__global__ __launch_bounds__(FBLK) void finalize_kernel(
    const float* __restrict__ partial, float* __restrict__ res,
    unsigned int* __restrict__ ticket, float* __restrict__ out) {
  const int w    = blockIdx.x;   // dir*8 + b
  const int dir  = w >> 3;
  const int b    = w & 7;
  const int wid  = threadIdx.x >> 6;   // 0..15
  const int lane = threadIdx.x & 63;

  __shared__ float rA[16], rB[16], rC[16], rD[16];

  const float4* pv = (const float4*)partial;
  const size_t vbase = ((size_t)dir * BATCH + b) * (NPTS / 4);
  const size_t cstr  = (size_t)2 * BATCH * (NPTS / 4);

  // 16 independent loads -> chunk-min for this thread's float4.
  float4 m = pv[vbase + threadIdx.x];
#pragma unroll
  for (int c = 1; c < NCHUNK; ++c) {
    float4 t = pv[vbase + (size_t)c * cstr + threadIdx.x];
    m.x = fminf(m.x, t.x); m.y = fminf(m.y, t.y);
    m.z = fminf(m.z, t.z); m.w = fminf(m.w, t.w);
  }
  float sum = (m.x + m.y) + (m.z + m.w);
  float ssq = (m.x * m.x + m.y * m.y) + (m.z * m.z + m.w * m.w);

  for (int off = 32; off; off >>= 1) sum += __shfl_xor(sum, off, 64);
  for (int off = 32; off; off >>= 1) ssq += __shfl_xor(ssq, off, 64);
  if (lane == 0) { rA[wid] = sum; rB[wid] = ssq; }
  __syncthreads();
  // fixed-order 16-way tree (all threads compute identically -> deterministic)
  sum = ((rA[0] + rA[1]) + (rA[2] + rA[3])) + ((rA[4] + rA[5]) + (rA[6] + rA[7]))
      + ((rA[8] + rA[9]) + (rA[10] + rA[11])) + ((rA[12] + rA[13]) + (rA[14] + rA[15]));
  ssq = ((rB[0] + rB[1]) + (rB[2] + rB[3])) + ((rB[4] + rB[5]) + (rB[6] + rB[7]))
      + ((rB[8] + rB[9]) + (rB[10] + rB[11])) + ((rB[12] + rB[13]) + (rB[14] + rB[15]));
  const float mean = sum / (float)NPTS;
  const float var  = (ssq - (float)NPTS * mean * mean) / (float)(NPTS - 1);
  const float neg_thr = -0.5f * sqrtf(fmaxf(var, 0.0f));

  float ksum = 0.0f, kcnt = 0.0f;
  if (m.x - mean > neg_thr) { ksum += m.x; kcnt += 1.0f; }
  if (m.y - mean > neg_thr) { ksum += m.y; kcnt += 1.0f; }
  if (m.z - mean > neg_thr) { ksum += m.z; kcnt += 1.0f; }
  if (m.w - mean > neg_thr) { ksum += m.w; kcnt += 1.0f; }
  for (int off = 32; off; off >>= 1) ksum += __shfl_xor(ksum, off, 64);
  for (int off = 32; off; off >>= 1) kcnt += __shfl_xor(kcnt, off, 64);
  if (lane == 0) { rC[wid] = ksum; rD[wid] = kcnt; }
  __syncthreads();

  if (threadIdx.x == 0) {
    ksum = ((rC[0] + rC[1]) + (rC[2] + rC[3])) + ((rC[4] + rC[5]) + (rC[6] + rC[7]))
         + ((rC[8] + rC[9]) + (rC[10] + rC[11])) + ((rC[12] + rC[13]) + (rC[14] + rC[15]));
    kcnt = ((rD[0] + rD[1]) + (rD[2] + rD[3])) + ((rD[4] + rD[5]) + (rD[6] + rD[7]))
         + ((rD[8] + rD[9]) + (rD[10] + rD[11])) + ((rD[12] + rD[13]) + (rD[14] + rD[15]));
    __hip_atomic_store(&res[w], ksum / kcnt, __ATOMIC_RELAXED,
                       __HIP_MEMORY_SCOPE_AGENT);
    __threadfence();  // release: res[w] visible before ticket bump
    unsigned int old = atomicAdd(ticket, 1u);  // device-scope by default
    if (old == 15u) {
      __threadfence();  // acquire: all res[] writes visible
      float tot = 0.0f;
      for (int i = 0; i < 16; ++i) {  // fixed order: bit-deterministic
        tot += __hip_atomic_load(&res[i], __ATOMIC_RELAXED,
                                 __HIP_MEMORY_SCOPE_AGENT);
      }
      out[0] = tot / (float)BATCH;
    }
  }
}

extern "C" void kernel_launch(void* const* d_in, const int* in_sizes, int n_in,
                              void* d_out, int out_size, void* d_ws, size_t ws_size,
                              hipStream_t stream) {
  const float* x = (const float*)d_in[0];
  const float* y = (const float*)d_in[1];
  float* out = (float*)d_out;
  float* partial = (float*)d_ws;                       // 16*2*8*4096*4B = 4 MB
  float* res = partial + (size_t)NCHUNK * 2 * BATCH * NPTS;  // 16 floats
  unsigned int* ticket = (unsigned int*)(res + 16);          // 1 uint

  dim3 g1(PGRP, BATCH, 2 * NCHUNK);
  dmin_kernel<<<g1, BLK, 0, stream>>>(x, y, partial, ticket);
  finalize_kernel<<<16, FBLK, 0, stream>>>(partial, res, ticket, out);
}